// Round 5
// baseline (21487.935 us; speedup 1.0000x reference)
//
#include <hip/hip_runtime.h>
#include <hip/hip_bf16.h>
#include <math.h>

#define N_WORDS 8192
#define LMAX    16
#define WED     506
#define WHD     512
#define CED     6
#define CHD     6
#define CVOC    128
#define TAG     64
#define XDIM    512      // WED + CHD
#define G4      2048     // 4*WHD
#define NWG     64       // workgroups for the word LSTM

__device__ __forceinline__ float fast_sigmoid(float x) { return 1.0f / (1.0f + __expf(-x)); }
__device__ __forceinline__ float fast_tanh(float x)    { return 2.0f / (1.0f + __expf(-2.0f * x)) - 1.0f; }

// ---------------- Kernel A: char-level LSTM, one thread per word ----------------
__global__ void __launch_bounds__(256) char_lstm_kernel(
    const int*   __restrict__ chars,     // [N, LMAX]
    const int*   __restrict__ lens,      // [N]
    const float* __restrict__ char_emb,  // [CVOC, CED]
    const float* __restrict__ cWih,      // [24, 6]
    const float* __restrict__ cWhh,      // [24, 6]
    const float* __restrict__ cb,        // [24]
    float*       __restrict__ h_char)    // [N, CHD]
{
    __shared__ float sWih[24][6], sWhh[24][6], sb[24], semb[CVOC][CED];
    int t = threadIdx.x;
    if (t < 144) { sWih[t / 6][t % 6] = cWih[t]; sWhh[t / 6][t % 6] = cWhh[t]; }
    if (t < 24) sb[t] = cb[t];
    for (int i = t; i < CVOC * CED; i += 256) semb[i / CED][i % CED] = char_emb[i];
    __syncthreads();

    int n = blockIdx.x * 256 + t;
    if (n >= N_WORDS) return;
    int len = lens[n];
    float h[CHD] = {0, 0, 0, 0, 0, 0};
    float c[CHD] = {0, 0, 0, 0, 0, 0};
    for (int l = 0; l < LMAX; ++l) {
        if (l >= len) break;  // once l >= len no further state updates occur
        int ch = chars[n * LMAX + l];
        float e[CED];
        #pragma unroll
        for (int k = 0; k < CED; ++k) e[k] = semb[ch][k];
        float pre[24];
        #pragma unroll
        for (int g = 0; g < 24; ++g) {
            float a = sb[g];
            #pragma unroll
            for (int k = 0; k < CED; ++k) a += e[k] * sWih[g][k];
            #pragma unroll
            for (int k = 0; k < CHD; ++k) a += h[k] * sWhh[g][k];
            pre[g] = a;
        }
        #pragma unroll
        for (int u = 0; u < CHD; ++u) {
            float ig = fast_sigmoid(pre[u]);
            float fg = fast_sigmoid(pre[6 + u]);
            float gg = fast_tanh(pre[12 + u]);
            float og = fast_sigmoid(pre[18 + u]);
            float cn = fg * c[u] + ig * gg;
            c[u] = cn;
            h[u] = og * fast_tanh(cn);
        }
    }
    for (int u = 0; u < CHD; ++u) h_char[n * CHD + u] = h[u];
}

// ---------------- Kernel B0: X = [word_emb gather | h_char] ----------------
__global__ void __launch_bounds__(256) build_x_kernel(
    const int*   __restrict__ words,
    const float* __restrict__ word_emb,  // [WV, WED]
    const float* __restrict__ h_char,    // [N, CHD]
    float*       __restrict__ X)         // [N, XDIM]
{
    long idx = (long)blockIdx.x * 256 + threadIdx.x;
    if (idx >= (long)N_WORDS * XDIM) return;
    int n = (int)(idx >> 9), k = (int)(idx & 511);
    float v;
    if (k < WED) v = word_emb[(long)words[n] * WED + k];
    else         v = h_char[n * CHD + (k - WED)];
    X[idx] = v;
}

// ---------------- Kernel B1: XP4 = X @ Wih^T + b, fp32 tiled GEMM ----------------
// Epilogue writes gate-interleaved layout XP4[t][unit][gate] so the word LSTM
// reads one float4 per thread per step.
#define BM 64
#define BN 64
#define BK 16
__global__ void __launch_bounds__(256) xp_gemm_kernel(
    const float* __restrict__ X,    // [N, 512]
    const float* __restrict__ Wih,  // [2048, 512]
    const float* __restrict__ wb,   // [2048]
    float*       __restrict__ XP4)  // [N, 512, 4]
{
    __shared__ float As[BM][BK + 1];
    __shared__ float Bs[BN][BK + 1];
    int tid = threadIdx.x;
    int bm = (blockIdx.x % (N_WORDS / BM)) * BM;
    int bn = (blockIdx.x / (N_WORDS / BM)) * BN;
    int ty = tid / 16, tx = tid % 16;
    float acc[4][4] = {};
    for (int k0 = 0; k0 < XDIM; k0 += BK) {
        #pragma unroll
        for (int i = 0; i < 4; ++i) {
            int e = tid + i * 256;
            int r = e >> 4, cc = e & 15;
            As[r][cc] = X[(long)(bm + r) * XDIM + k0 + cc];
            Bs[r][cc] = Wih[(long)(bn + r) * XDIM + k0 + cc];
        }
        __syncthreads();
        #pragma unroll
        for (int kk = 0; kk < BK; ++kk) {
            float a[4], b[4];
            #pragma unroll
            for (int i = 0; i < 4; ++i) a[i] = As[ty * 4 + i][kk];
            #pragma unroll
            for (int j = 0; j < 4; ++j) b[j] = Bs[tx * 4 + j][kk];
            #pragma unroll
            for (int i = 0; i < 4; ++i)
                #pragma unroll
                for (int j = 0; j < 4; ++j) acc[i][j] += a[i] * b[j];
        }
        __syncthreads();
    }
    #pragma unroll
    for (int i = 0; i < 4; ++i) {
        int m = bm + ty * 4 + i;
        #pragma unroll
        for (int j = 0; j < 4; ++j) {
            int g = bn + tx * 4 + j;
            int unit = g & 511, gate = g >> 9;
            XP4[((long)m * WHD + unit) * 4 + gate] = acc[i][j] + wb[g];
        }
    }
}

// ---------------- Kernel C: sequential word LSTM (R0 + private mailboxes) ----------
// 64 WGs x 256 threads, R0 structure. Transport change only: producers PUSH h to
// every consumer's PRIVATE mailbox row, so each WG polls its OWN 2KB (disjoint LLC
// lines -> no same-line read fan-in, the hypothesized RTT inflator).
//  MB layout: [parity=t&1][consumer=64][unit=512] floats.
//  Value protocol: store s*(h+2), s = ((t>>1)&1) ? -1 : +1. Ready for step t-1:
//  s_{t-1}*v > 0.5. Parity buffer separates t-1 from t-2; the sign separates t-1
//  from t-3 (same buffer); t-5 aliasing is impossible because this consumer already
//  OBSERVED t-3 in the same slot at its step t-2 (per-location coherence is
//  monotone). Overwrite-before-consume cannot happen: a producer writing step t
//  into buffer b has necessarily seen ALL of row t-1, which proves every WG
//  finished step t-1 and therefore consumed its t-2 values from buffer b.
//  MB is memset to 0 (fails both sign bands) before launch.
// Each lane holds its unit's h after the butterfly reduce, so the fan-out costs
// 2 scattered 4B stores per thread and ZERO extra barriers. HS keeps plain stores
// (h+2.0) for the logits kernel; it is no longer part of the sync protocol.
__global__ void __launch_bounds__(256, 1) word_lstm_kernel(
    const float* __restrict__ Whh,  // [2048, 512]
    const float* __restrict__ XP4,  // [N, 512, 4] gate-interleaved
    float*       HS,                // [N, 512]; stores h+2.0 (plain) for logits
    float*       MB)                // [2][64][512] mailboxes; pre-zeroed
{
    __shared__ float hbuf[WHD];     // h[t-1] (offset removed)

    const int tid = threadIdx.x;
    const int wg  = blockIdx.x;      // 0..63 (= consumer id)
    const int ug  = tid >> 5;        // 0..7 unit-in-block
    const int p   = tid & 31;        // K-part within unit
    const int j   = wg * 8 + ug;     // hidden unit 0..511

    // weights for the strided K-set
    float w[4][16];
    #pragma unroll
    for (int r = 0; r < 4; ++r) {
        const float* src = Whh + (long)(r * 512 + j) * WHD + p;
        #pragma unroll
        for (int kk = 0; kk < 16; ++kk) w[r][kk] = src[kk * 32];
    }

    float c = 0.0f;
    float h16[16];
    #pragma unroll
    for (int kk = 0; kk < 16; ++kk) h16[kk] = 0.0f;

    for (int t = 0; t < N_WORDS; ++t) {
        // xp load depends only on t -> issue before the poll so HBM latency hides
        const float4 xp = *(const float4*)(XP4 + ((long)t * WHD + j) * 4);

        if (t > 0) {
            const float sgp = (((t - 1) >> 1) & 1) ? -1.0f : 1.0f;
            if (tid < 64) {
                // poll OUR private mailbox row for step t-1
                const unsigned long long* hrow = (const unsigned long long*)
                    (MB + (size_t)((t - 1) & 1) * 64 * WHD + (size_t)wg * WHD);
                float lo[4], hi[4];
                bool ready = false;
                while (!ready) {
                    unsigned long long q[4];
                    #pragma unroll
                    for (int i = 0; i < 4; ++i)
                        q[i] = __hip_atomic_load(&hrow[i * 64 + tid], __ATOMIC_RELAXED,
                                                 __HIP_MEMORY_SCOPE_AGENT);
                    ready = true;
                    #pragma unroll
                    for (int i = 0; i < 4; ++i) {
                        lo[i] = sgp * __uint_as_float((unsigned)(q[i] & 0xffffffffu));
                        hi[i] = sgp * __uint_as_float((unsigned)(q[i] >> 32));
                        ready = ready && (lo[i] > 0.5f) && (hi[i] > 0.5f);
                    }
                }
                #pragma unroll
                for (int i = 0; i < 4; ++i) {
                    hbuf[i * 128 + 2 * tid]     = lo[i] - 2.0f;
                    hbuf[i * 128 + 2 * tid + 1] = hi[i] - 2.0f;
                }
            }
            __syncthreads();
            #pragma unroll
            for (int kk = 0; kk < 16; ++kk) h16[kk] = hbuf[p + 32 * kk];
        }

        float di = 0, df = 0, dg = 0, dq = 0;
        #pragma unroll
        for (int kk = 0; kk < 16; ++kk) {
            di = fmaf(w[0][kk], h16[kk], di);
            df = fmaf(w[1][kk], h16[kk], df);
            dg = fmaf(w[2][kk], h16[kk], dg);
            dq = fmaf(w[3][kk], h16[kk], dq);
        }
        // reduce over the 32 lanes of this unit (xor masks <32 stay in each half-wave)
        #pragma unroll
        for (int m = 16; m >= 1; m >>= 1) {
            di += __shfl_xor(di, m);
            df += __shfl_xor(df, m);
            dg += __shfl_xor(dg, m);
            dq += __shfl_xor(dq, m);
        }
        float ig = fast_sigmoid(xp.x + di);
        float fg = fast_sigmoid(xp.y + df);
        float gg = fast_tanh(xp.z + dg);
        float og = fast_sigmoid(xp.w + dq);
        c = fg * c + ig * gg;
        float hn = og * fast_tanh(c);

        // fan-out: every lane has hn for its unit; deliver to consumers p and p+32.
        {
            const float sg = ((t >> 1) & 1) ? -1.0f : 1.0f;
            const float sv = sg * (hn + 2.0f);
            float* mb = MB + (size_t)(t & 1) * 64 * WHD;
            __hip_atomic_store(&mb[(size_t)p * WHD + j], sv, __ATOMIC_RELAXED,
                               __HIP_MEMORY_SCOPE_AGENT);
            __hip_atomic_store(&mb[(size_t)(p + 32) * WHD + j], sv, __ATOMIC_RELAXED,
                               __HIP_MEMORY_SCOPE_AGENT);
            if (p == 0) HS[(long)t * WHD + j] = hn + 2.0f;   // logits input, off-path
        }
        // NOTE: no trailing barrier needed. Wave 0 only overwrites hbuf for step t+1
        // after its whole mailbox row t is visible, which implies every wave
        // (including ours) has already consumed its step-t LDS reads.
    }
}

// ---------------- Kernel D0: transpose out_W to [512][64] for coalesced reads ----------------
__global__ void __launch_bounds__(256) transpose_outw_kernel(
    const float* __restrict__ outW, float* __restrict__ outWT)
{
    int e = blockIdx.x * 256 + threadIdx.x;  // TAG*WHD
    if (e >= TAG * WHD) return;
    int g = e >> 9, k = e & 511;
    outWT[k * TAG + g] = outW[e];
}

// ---------------- Kernel D: logits + log_softmax, one wave per word ----------------
// HS holds h+2.0 -> subtract the offset inline.
__global__ void __launch_bounds__(64) logits_kernel(
    const float* __restrict__ HS,
    const float* __restrict__ outWT,   // [512][64]
    const float* __restrict__ outb,    // [64]
    float*       __restrict__ out)     // [N, 64]
{
    int n = blockIdx.x;
    int g = threadIdx.x;
    const float* hrow = HS + (long)n * WHD;
    float acc = outb[g];
    #pragma unroll 8
    for (int k = 0; k < WHD; ++k) acc += (hrow[k] - 2.0f) * outWT[k * TAG + g];
    float m = acc;
    #pragma unroll
    for (int s = 32; s >= 1; s >>= 1) m = fmaxf(m, __shfl_xor(m, s));
    float ex = __expf(acc - m);
    float ssum = ex;
    #pragma unroll
    for (int s = 32; s >= 1; s >>= 1) ssum += __shfl_xor(ssum, s);
    out[(long)n * TAG + g] = acc - m - logf(ssum);
}

extern "C" void kernel_launch(void* const* d_in, const int* in_sizes, int n_in,
                              void* d_out, int out_size, void* d_ws, size_t ws_size,
                              hipStream_t stream)
{
    const int*   words = (const int*)   d_in[0];
    const int*   chars = (const int*)   d_in[1];
    const int*   lens  = (const int*)   d_in[2];
    const float* wemb  = (const float*) d_in[3];
    const float* cemb  = (const float*) d_in[4];
    const float* cWih  = (const float*) d_in[5];
    const float* cWhh  = (const float*) d_in[6];
    const float* cb    = (const float*) d_in[7];
    const float* wWih  = (const float*) d_in[8];
    const float* wWhh  = (const float*) d_in[9];
    const float* wb    = (const float*) d_in[10];
    const float* outW  = (const float*) d_in[11];
    const float* outb  = (const float*) d_in[12];
    float* out = (float*)d_out;

    // workspace layout (bytes)
    char* ws = (char*)d_ws;
    size_t off = 0;
    float* h_char = (float*)(ws + off); off += (size_t)N_WORDS * CHD * 4;      // 196,608
    float* X      = (float*)(ws + off); off += (size_t)N_WORDS * XDIM * 4;     // 16.8 MB
    float* XP4    = (float*)(ws + off); off += (size_t)N_WORDS * G4 * 4;       // 67.1 MB
    float* HS     = (float*)(ws + off); off += (size_t)N_WORDS * WHD * 4;      // 16.8 MB
    float* outWT  = (float*)(ws + off); off += (size_t)WHD * TAG * 4;          // 128 KB
    float* MB     = (float*)(ws + off); off += (size_t)2 * NWG * WHD * 4;      // 256 KB

    // MB must be zero so the sign-band protocol is well-defined at t=0/1.
    hipMemsetAsync(MB, 0, (size_t)2 * NWG * WHD * sizeof(float), stream);
    // HS is no longer a sentinel, but keep it zeroed (cheap, removes any garbage).
    hipMemsetAsync(HS, 0, (size_t)N_WORDS * WHD * sizeof(float), stream);

    char_lstm_kernel<<<N_WORDS / 256, 256, 0, stream>>>(chars, lens, cemb, cWih, cWhh, cb, h_char);
    build_x_kernel<<<(N_WORDS * XDIM) / 256, 256, 0, stream>>>(words, wemb, h_char, X);
    xp_gemm_kernel<<<(N_WORDS / BM) * (G4 / BN), 256, 0, stream>>>(X, wWih, wb, XP4);
    transpose_outw_kernel<<<(TAG * WHD) / 256, 256, 0, stream>>>(outW, outWT);
    word_lstm_kernel<<<NWG, 256, 0, stream>>>(wWhh, XP4, HS, MB);
    logits_kernel<<<N_WORDS, 64, 0, stream>>>(HS, outWT, outb, out);
}